// Round 1
// baseline (1056.045 us; speedup 1.0000x reference)
//
#include <hip/hip_runtime.h>

#define N_NODES 100000
#define N_EDGES 1600000

constexpr int SCAN_THREADS = 1024;
constexpr int CHUNK = (N_NODES + SCAN_THREADS - 1) / SCAN_THREADS; // 98

// ---------------- CSR build ----------------

__global__ void count_kernel(const int* __restrict__ ei, int* __restrict__ deg) {
    int e = blockIdx.x * 256 + threadIdx.x;
    if (e < N_EDGES) atomicAdd(&deg[ei[N_EDGES + e]], 1);
}

__global__ __launch_bounds__(SCAN_THREADS)
void scan_kernel(const int* __restrict__ deg, int* __restrict__ off,
                 int* __restrict__ cursor, float* __restrict__ dinv) {
    __shared__ int wsum[16];
    int t = threadIdx.x;
    int lane = t & 63, w = t >> 6;
    int start = t * CHUNK;
    int end = min(start + CHUNK, N_NODES);
    int s = 0;
    for (int i = start; i < end; ++i) s += deg[i];
    // wave-64 inclusive scan
    int incl = s;
    #pragma unroll
    for (int d = 1; d < 64; d <<= 1) {
        int v = __shfl_up(incl, d);
        if (lane >= d) incl += v;
    }
    if (lane == 63) wsum[w] = incl;
    __syncthreads();
    if (t < 16) {
        int v = wsum[t];
        int iv = v;
        #pragma unroll
        for (int d = 1; d < 16; d <<= 1) {
            int u = __shfl_up(iv, d, 16);
            if (t >= d) iv += u;
        }
        wsum[t] = iv - v; // exclusive wave base
    }
    __syncthreads();
    int base = wsum[w] + (incl - s);
    int run = base;
    for (int i = start; i < end; ++i) {
        off[i] = run;
        cursor[i] = run;
        int dg = deg[i];
        dinv[i] = 1.0f / (float)max(dg, 1);
        run += dg;
    }
    if (start < N_NODES && end == N_NODES) off[N_NODES] = run;
}

__global__ void fill_kernel(const int* __restrict__ ei, int* __restrict__ cursor,
                            int* __restrict__ ssrc) {
    int e = blockIdx.x * 256 + threadIdx.x;
    if (e < N_EDGES) {
        int d = ei[N_EDGES + e];
        int p = atomicAdd(&cursor[d], 1);
        ssrc[p] = ei[e];
    }
}

// ---------------- GEMM: out[N, COUT] = H[N,128] @ W[COUT,128]^T (+bias) ----------------
// One block = 64 rows x full COUT. Safe for in-place out==H (block reads only its own rows,
// all reads precede epilogue stores; no column tiling so no cross-block row sharing).

__device__ inline void fma4(float4& c, float s, const float4& b) {
    c.x += s * b.x; c.y += s * b.y; c.z += s * b.z; c.w += s * b.w;
}

template<int COUT, bool BIAS>
__global__ __launch_bounds__(256)
void gemm_kernel(const float* H, const float* __restrict__ W,
                 const float* __restrict__ bias, float* out) {
    constexpr int NF4 = COUT / 64;          // float4 column groups per thread
    __shared__ float As[32][64];            // k-major A tile
    __shared__ float Bs[32][COUT];          // k-major B tile (W^T)
    int t = threadIdx.x;
    int tx = t & 15, ty = t >> 4;
    int r0 = blockIdx.x * 64;

    float4 acc[4][NF4];
    #pragma unroll
    for (int i = 0; i < 4; ++i)
        #pragma unroll
        for (int h = 0; h < NF4; ++h)
            acc[i][h] = make_float4(0.f, 0.f, 0.f, 0.f);

    for (int k0 = 0; k0 < 128; k0 += 32) {
        // stage A: 64 rows x 32 k  (512 float4, 2 per thread), coalesced global reads
        #pragma unroll
        for (int it = 0; it < 2; ++it) {
            int lin = t + it * 256;
            int r = lin >> 3, kq = lin & 7;
            int row = r0 + r;
            float4 v = make_float4(0.f, 0.f, 0.f, 0.f);
            if (row < N_NODES)
                v = *reinterpret_cast<const float4*>(&H[(size_t)row * 128 + k0 + kq * 4]);
            As[kq * 4 + 0][r] = v.x;
            As[kq * 4 + 1][r] = v.y;
            As[kq * 4 + 2][r] = v.z;
            As[kq * 4 + 3][r] = v.w;
        }
        // stage B: COUT rows x 32 k
        #pragma unroll
        for (int it = 0; it < COUT * 8 / 256; ++it) {
            int lin = t + it * 256;
            int c = lin >> 3, kq = lin & 7;
            float4 v = *reinterpret_cast<const float4*>(&W[(size_t)c * 128 + k0 + kq * 4]);
            Bs[kq * 4 + 0][c] = v.x;
            Bs[kq * 4 + 1][c] = v.y;
            Bs[kq * 4 + 2][c] = v.z;
            Bs[kq * 4 + 3][c] = v.w;
        }
        __syncthreads();
        #pragma unroll
        for (int k = 0; k < 32; ++k) {
            float4 a = *reinterpret_cast<const float4*>(&As[k][ty * 4]);
            #pragma unroll
            for (int h = 0; h < NF4; ++h) {
                float4 b = *reinterpret_cast<const float4*>(&Bs[k][tx * 4 + h * 64]);
                fma4(acc[0][h], a.x, b);
                fma4(acc[1][h], a.y, b);
                fma4(acc[2][h], a.z, b);
                fma4(acc[3][h], a.w, b);
            }
        }
        __syncthreads();
    }

    #pragma unroll
    for (int h = 0; h < NF4; ++h) {
        float4 bb = make_float4(0.f, 0.f, 0.f, 0.f);
        if (BIAS) bb = *reinterpret_cast<const float4*>(&bias[tx * 4 + h * 64]);
        #pragma unroll
        for (int i = 0; i < 4; ++i) {
            int row = r0 + ty * 4 + i;
            if (row < N_NODES) {
                float4 v = acc[i][h];
                v.x += bb.x; v.y += bb.y; v.z += bb.z; v.w += bb.w;
                *reinterpret_cast<float4*>(&out[(size_t)row * COUT + tx * 4 + h * 64]) = v;
            }
        }
    }
}

// ---------------- Aggregate: out[i] = relu?(deg_inv[i] * sum_{p} Y[ssrc[p]] + out[i]) ----------------
// out already holds z = h @ W_r.T + b (in-place elementwise update).

template<int COUT, bool RELU>
__global__ __launch_bounds__(256)
void agg_kernel(const float* __restrict__ Y, const int* __restrict__ off,
                const int* __restrict__ ssrc, const float* __restrict__ dinv,
                float* out) {
    constexpr int CQ = COUT / 4;
    int tid = blockIdx.x * 256 + threadIdx.x;
    int i = tid / CQ, cq = tid % CQ;
    if (i >= N_NODES) return;
    int p0 = off[i], p1 = off[i + 1];
    float4 acc = make_float4(0.f, 0.f, 0.f, 0.f);
    for (int p = p0; p < p1; ++p) {
        int s = ssrc[p];
        float4 v = *reinterpret_cast<const float4*>(&Y[(size_t)s * COUT + cq * 4]);
        acc.x += v.x; acc.y += v.y; acc.z += v.z; acc.w += v.w;
    }
    float di = dinv[i];
    float4 z = *reinterpret_cast<const float4*>(&out[(size_t)i * COUT + cq * 4]);
    float4 r;
    r.x = acc.x * di + z.x;
    r.y = acc.y * di + z.y;
    r.z = acc.z * di + z.z;
    r.w = acc.w * di + z.w;
    if (RELU) {
        r.x = fmaxf(r.x, 0.f); r.y = fmaxf(r.y, 0.f);
        r.z = fmaxf(r.z, 0.f); r.w = fmaxf(r.w, 0.f);
    }
    *reinterpret_cast<float4*>(&out[(size_t)i * COUT + cq * 4]) = r;
}

// ---------------- launch ----------------

extern "C" void kernel_launch(void* const* d_in, const int* in_sizes, int n_in,
                              void* d_out, int out_size, void* d_ws, size_t ws_size,
                              hipStream_t stream) {
    const float* x   = (const float*)d_in[0];
    const int*   ei  = (const int*)d_in[2];
    const float* Wl0 = (const float*)d_in[3];
    const float* bl0 = (const float*)d_in[4];
    const float* Wr0 = (const float*)d_in[5];
    const float* Wl1 = (const float*)d_in[6];
    const float* bl1 = (const float*)d_in[7];
    const float* Wr1 = (const float*)d_in[8];
    const float* Wl2 = (const float*)d_in[9];
    const float* bl2 = (const float*)d_in[10];
    const float* Wr2 = (const float*)d_in[11];
    float* out = (float*)d_out;

    char* ws = (char*)d_ws;
    int*   deg    = (int*)(ws + 0);                         // 400 KB
    int*   off    = (int*)(ws + (size_t)(1 << 20));         // 400 KB (+1)
    int*   cursor = (int*)(ws + (size_t)(2 << 20));         // 400 KB
    float* dinv   = (float*)(ws + (size_t)(3 << 20));       // 400 KB
    int*   ssrc   = (int*)(ws + (size_t)(4 << 20));         // 6.4 MB
    float* bufA   = (float*)(ws + (size_t)(12 << 20));      // 51.2 MB (y)
    float* bufB   = (float*)(ws + (size_t)(12 << 20) + (size_t)(50 << 20)); // 51.2 MB (h)

    hipMemsetAsync(deg, 0, sizeof(int) * N_NODES, stream);

    int egrid = (N_EDGES + 255) / 256;
    count_kernel<<<egrid, 256, 0, stream>>>(ei, deg);
    scan_kernel<<<1, SCAN_THREADS, 0, stream>>>(deg, off, cursor, dinv);
    fill_kernel<<<egrid, 256, 0, stream>>>(ei, cursor, ssrc);

    int ggrid = (N_NODES + 63) / 64;                 // 1563
    int agrid128 = (N_NODES * 32 + 255) / 256;       // 12500
    int agrid64  = (N_NODES * 16 + 255) / 256;       // 6250

    // layer 0: h = x
    gemm_kernel<128, false><<<ggrid, 256, 0, stream>>>(x, Wl0, nullptr, bufA);
    gemm_kernel<128, true ><<<ggrid, 256, 0, stream>>>(x, Wr0, bl0, bufB);
    agg_kernel<128, true><<<agrid128, 256, 0, stream>>>(bufA, off, ssrc, dinv, bufB);

    // layer 1: h = bufB (z GEMM in-place on bufB)
    gemm_kernel<128, false><<<ggrid, 256, 0, stream>>>(bufB, Wl1, nullptr, bufA);
    gemm_kernel<128, true ><<<ggrid, 256, 0, stream>>>(bufB, Wr1, bl1, bufB);
    agg_kernel<128, true><<<agrid128, 256, 0, stream>>>(bufA, off, ssrc, dinv, bufB);

    // layer 2: h = bufB, output to d_out
    gemm_kernel<64, false><<<ggrid, 256, 0, stream>>>(bufB, Wl2, nullptr, bufA);
    gemm_kernel<64, true ><<<ggrid, 256, 0, stream>>>(bufB, Wr2, bl2, out);
    agg_kernel<64, false><<<agrid64, 256, 0, stream>>>(bufA, off, ssrc, dinv, out);
}

// Round 2
// 777.474 us; speedup vs baseline: 1.3583x; 1.3583x over previous
//
#include <hip/hip_runtime.h>

#define N_NODES 100000
#define N_EDGES 1600000

constexpr int NBLK = (N_NODES + 255) / 256; // 391

// ---------------- CSR build ----------------

__global__ void count_kernel(const int* __restrict__ ei, int* __restrict__ deg) {
    int e = blockIdx.x * 256 + threadIdx.x;
    if (e < N_EDGES) atomicAdd(&deg[ei[N_EDGES + e]], 1);
}

// per-256-node block sums
__global__ __launch_bounds__(256)
void blocksum_kernel(const int* __restrict__ deg, int* __restrict__ bsum) {
    __shared__ int wsum[4];
    int t = threadIdx.x, lane = t & 63, w = t >> 6;
    int i = blockIdx.x * 256 + t;
    int v = (i < N_NODES) ? deg[i] : 0;
    #pragma unroll
    for (int d = 32; d >= 1; d >>= 1) v += __shfl_xor(v, d);
    if (lane == 0) wsum[w] = v;
    __syncthreads();
    if (t == 0) bsum[blockIdx.x] = wsum[0] + wsum[1] + wsum[2] + wsum[3];
}

// single small block: exclusive scan of NBLK block sums
__global__ __launch_bounds__(512)
void scanblk_kernel(const int* __restrict__ bsum, int* __restrict__ bbase,
                    int* __restrict__ off) {
    __shared__ int wsum[8];
    int t = threadIdx.x, lane = t & 63, w = t >> 6;
    int v = (t < NBLK) ? bsum[t] : 0;
    int incl = v;
    #pragma unroll
    for (int d = 1; d < 64; d <<= 1) {
        int u = __shfl_up(incl, d);
        if (lane >= d) incl += u;
    }
    if (lane == 63) wsum[w] = incl;
    __syncthreads();
    if (t < 8) {
        int s = wsum[t];
        int iv = s;
        #pragma unroll
        for (int d = 1; d < 8; d <<= 1) {
            int u = __shfl_up(iv, d, 8);
            if (t >= d) iv += u;
        }
        wsum[t] = iv - s; // exclusive
    }
    __syncthreads();
    if (t < NBLK) bbase[t] = wsum[w] + (incl - v);
    if (t == 0) off[N_NODES] = N_EDGES;
}

// finalize: per-node exclusive offsets + cursor + deg_inv
__global__ __launch_bounds__(256)
void finalize_kernel(const int* __restrict__ deg, const int* __restrict__ bbase,
                     int* __restrict__ off, int* __restrict__ cursor,
                     float* __restrict__ dinv) {
    __shared__ int wsum[4];
    int t = threadIdx.x, lane = t & 63, w = t >> 6;
    int i = blockIdx.x * 256 + t;
    int v = (i < N_NODES) ? deg[i] : 0;
    int incl = v;
    #pragma unroll
    for (int d = 1; d < 64; d <<= 1) {
        int u = __shfl_up(incl, d);
        if (lane >= d) incl += u;
    }
    if (lane == 63) wsum[w] = incl;
    __syncthreads();
    if (t < 4) {
        int s = wsum[t];
        int iv = s;
        #pragma unroll
        for (int d = 1; d < 4; d <<= 1) {
            int u = __shfl_up(iv, d, 4);
            if (t >= d) iv += u;
        }
        wsum[t] = iv - s;
    }
    __syncthreads();
    if (i < N_NODES) {
        int excl = bbase[blockIdx.x] + wsum[w] + (incl - v);
        off[i] = excl;
        cursor[i] = excl;
        dinv[i] = 1.0f / (float)max(v, 1);
    }
}

__global__ void fill_kernel(const int* __restrict__ ei, int* __restrict__ cursor,
                            int* __restrict__ ssrc) {
    int e = blockIdx.x * 256 + threadIdx.x;
    if (e < N_EDGES) {
        int d = ei[N_EDGES + e];
        int p = atomicAdd(&cursor[d], 1);
        ssrc[p] = ei[e];
    }
}

// ---------------- Fused dual GEMM ----------------
// out1[N,C1] = H @ W1^T          (no bias)
// out2[N,C2] = H @ W2^T + bias2
// One block = 64 rows x (C1+C2) cols. In-place safe for out2 == H.

__device__ inline void fma4(float4& c, float s, const float4& b) {
    c.x += s * b.x; c.y += s * b.y; c.z += s * b.z; c.w += s * b.w;
}

template<int C1, int C2>
__global__ __launch_bounds__(256)
void gemm2_kernel(const float* H, const float* __restrict__ W1,
                  const float* __restrict__ W2, const float* __restrict__ bias2,
                  float* out1, float* out2) {
    constexpr int COUT = C1 + C2;
    constexpr int NF4 = COUT / 64;
    __shared__ float As[32][64];
    __shared__ float Bs[32][COUT];
    int t = threadIdx.x;
    int tx = t & 15, ty = t >> 4;
    int r0 = blockIdx.x * 64;

    float4 acc[4][NF4];
    #pragma unroll
    for (int i = 0; i < 4; ++i)
        #pragma unroll
        for (int h = 0; h < NF4; ++h)
            acc[i][h] = make_float4(0.f, 0.f, 0.f, 0.f);

    for (int k0 = 0; k0 < 128; k0 += 32) {
        #pragma unroll
        for (int it = 0; it < 2; ++it) {
            int lin = t + it * 256;
            int r = lin >> 3, kq = lin & 7;
            int row = r0 + r;
            float4 v = make_float4(0.f, 0.f, 0.f, 0.f);
            if (row < N_NODES)
                v = *reinterpret_cast<const float4*>(&H[(size_t)row * 128 + k0 + kq * 4]);
            As[kq * 4 + 0][r] = v.x;
            As[kq * 4 + 1][r] = v.y;
            As[kq * 4 + 2][r] = v.z;
            As[kq * 4 + 3][r] = v.w;
        }
        #pragma unroll
        for (int it = 0; it < COUT * 8 / 256; ++it) {
            int lin = t + it * 256;
            int c = lin >> 3, kq = lin & 7;
            const float* Wp = (c < C1) ? &W1[(size_t)c * 128]
                                       : &W2[(size_t)(c - C1) * 128];
            float4 v = *reinterpret_cast<const float4*>(&Wp[k0 + kq * 4]);
            Bs[kq * 4 + 0][c] = v.x;
            Bs[kq * 4 + 1][c] = v.y;
            Bs[kq * 4 + 2][c] = v.z;
            Bs[kq * 4 + 3][c] = v.w;
        }
        __syncthreads();
        #pragma unroll
        for (int k = 0; k < 32; ++k) {
            float4 a = *reinterpret_cast<const float4*>(&As[k][ty * 4]);
            #pragma unroll
            for (int h = 0; h < NF4; ++h) {
                float4 b = *reinterpret_cast<const float4*>(&Bs[k][tx * 4 + h * 64]);
                fma4(acc[0][h], a.x, b);
                fma4(acc[1][h], a.y, b);
                fma4(acc[2][h], a.z, b);
                fma4(acc[3][h], a.w, b);
            }
        }
        __syncthreads();
    }

    #pragma unroll
    for (int h = 0; h < NF4; ++h) {
        int colbase = h * 64;           // whole h-group lives in one output
        bool is1 = (colbase < C1);
        int col = tx * 4 + (is1 ? colbase : colbase - C1);
        float4 bb = make_float4(0.f, 0.f, 0.f, 0.f);
        if (!is1) bb = *reinterpret_cast<const float4*>(&bias2[col]);
        float* dst = is1 ? out1 : out2;
        int cw = is1 ? C1 : C2;
        #pragma unroll
        for (int i = 0; i < 4; ++i) {
            int row = r0 + ty * 4 + i;
            if (row < N_NODES) {
                float4 v = acc[i][h];
                v.x += bb.x; v.y += bb.y; v.z += bb.z; v.w += bb.w;
                *reinterpret_cast<float4*>(&dst[(size_t)row * cw + col]) = v;
            }
        }
    }
}

// ---------------- Aggregate: out[i] = relu?(deg_inv[i] * sum_p Y[ssrc[p]] + out[i]) ----------------

template<int COUT, bool RELU>
__global__ __launch_bounds__(256)
void agg_kernel(const float* __restrict__ Y, const int* __restrict__ off,
                const int* __restrict__ ssrc, const float* __restrict__ dinv,
                float* out) {
    constexpr int CQ = COUT / 4;
    int tid = blockIdx.x * 256 + threadIdx.x;
    int i = tid / CQ, cq = tid % CQ;
    if (i >= N_NODES) return;
    int p0 = off[i], p1 = off[i + 1];
    float4 acc = make_float4(0.f, 0.f, 0.f, 0.f);
    for (int p = p0; p < p1; ++p) {
        int s = ssrc[p];
        float4 v = *reinterpret_cast<const float4*>(&Y[(size_t)s * COUT + cq * 4]);
        acc.x += v.x; acc.y += v.y; acc.z += v.z; acc.w += v.w;
    }
    float di = dinv[i];
    float4 z = *reinterpret_cast<const float4*>(&out[(size_t)i * COUT + cq * 4]);
    float4 r;
    r.x = acc.x * di + z.x;
    r.y = acc.y * di + z.y;
    r.z = acc.z * di + z.z;
    r.w = acc.w * di + z.w;
    if (RELU) {
        r.x = fmaxf(r.x, 0.f); r.y = fmaxf(r.y, 0.f);
        r.z = fmaxf(r.z, 0.f); r.w = fmaxf(r.w, 0.f);
    }
    *reinterpret_cast<float4*>(&out[(size_t)i * COUT + cq * 4]) = r;
}

// ---------------- launch ----------------

extern "C" void kernel_launch(void* const* d_in, const int* in_sizes, int n_in,
                              void* d_out, int out_size, void* d_ws, size_t ws_size,
                              hipStream_t stream) {
    const float* x   = (const float*)d_in[0];
    const int*   ei  = (const int*)d_in[2];
    const float* Wl0 = (const float*)d_in[3];
    const float* bl0 = (const float*)d_in[4];
    const float* Wr0 = (const float*)d_in[5];
    const float* Wl1 = (const float*)d_in[6];
    const float* bl1 = (const float*)d_in[7];
    const float* Wr1 = (const float*)d_in[8];
    const float* Wl2 = (const float*)d_in[9];
    const float* bl2 = (const float*)d_in[10];
    const float* Wr2 = (const float*)d_in[11];
    float* out = (float*)d_out;

    char* ws = (char*)d_ws;
    int*   deg    = (int*)(ws + 0);                         // 400 KB
    int*   off    = (int*)(ws + (size_t)(1 << 20));         // 400 KB (+1)
    int*   cursor = (int*)(ws + (size_t)(2 << 20));         // 400 KB
    float* dinv   = (float*)(ws + (size_t)(3 << 20));       // 400 KB
    int*   bsum   = (int*)(ws + (size_t)(7 << 20) / 2);     // small
    int*   bbase  = (int*)(ws + (size_t)(15 << 20) / 4);    // small
    int*   ssrc   = (int*)(ws + (size_t)(4 << 20));         // 6.4 MB
    float* bufA   = (float*)(ws + (size_t)(12 << 20));      // 51.2 MB (y)
    float* bufB   = (float*)(ws + (size_t)(12 << 20) + (size_t)(50 << 20)); // 51.2 MB (h)

    hipMemsetAsync(deg, 0, sizeof(int) * N_NODES, stream);

    int egrid = (N_EDGES + 255) / 256;
    count_kernel<<<egrid, 256, 0, stream>>>(ei, deg);
    blocksum_kernel<<<NBLK, 256, 0, stream>>>(deg, bsum);
    scanblk_kernel<<<1, 512, 0, stream>>>(bsum, bbase, off);
    finalize_kernel<<<NBLK, 256, 0, stream>>>(deg, bbase, off, cursor, dinv);
    fill_kernel<<<egrid, 256, 0, stream>>>(ei, cursor, ssrc);

    int ggrid = (N_NODES + 63) / 64;                 // 1563
    int agrid128 = (N_NODES * 32 + 255) / 256;       // 12500
    int agrid64  = (N_NODES * 16 + 255) / 256;       // 6250

    // layer 0: h = x
    gemm2_kernel<128, 128><<<ggrid, 256, 0, stream>>>(x, Wl0, Wr0, bl0, bufA, bufB);
    agg_kernel<128, true><<<agrid128, 256, 0, stream>>>(bufA, off, ssrc, dinv, bufB);

    // layer 1: h = bufB (Z in-place on bufB)
    gemm2_kernel<128, 128><<<ggrid, 256, 0, stream>>>(bufB, Wl1, Wr1, bl1, bufA, bufB);
    agg_kernel<128, true><<<agrid128, 256, 0, stream>>>(bufA, off, ssrc, dinv, bufB);

    // layer 2: h = bufB, Z to d_out
    gemm2_kernel<64, 64><<<ggrid, 256, 0, stream>>>(bufB, Wl2, Wr2, bl2, bufA, out);
    agg_kernel<64, false><<<agrid64, 256, 0, stream>>>(bufA, off, ssrc, dinv, out);
}

// Round 3
// 617.826 us; speedup vs baseline: 1.7093x; 1.2584x over previous
//
#include <hip/hip_runtime.h>
#include <cstdint>

#define N_NODES 100000
#define N_EDGES 1600000

constexpr int NBLK = (N_NODES + 255) / 256; // 391

typedef __attribute__((ext_vector_type(8))) short short8;
typedef __attribute__((ext_vector_type(4))) float f32x4;

__device__ inline uint32_t fbits(float f) { union { float f; uint32_t u; } c; c.f = f; return c.u; }
__device__ inline float bfloat(uint32_t u) { union { uint32_t u; float f; } c; c.u = u; return c.f; }

// split fp32 a -> bf16 hi (truncate) + bf16 lo (truncated residual); a ~= hi+lo, err ~2^-16|a|
__device__ inline void bsplit(float a, short& hi, short& lo) {
    uint32_t h = fbits(a) & 0xFFFF0000u;
    float fl = a - bfloat(h);
    hi = (short)(h >> 16);
    lo = (short)(fbits(fl) >> 16);
}

__device__ inline ushort f2bf(float f) { // round-to-nearest-even fp32->bf16
    uint32_t u = fbits(f);
    return (ushort)((u + 0x7FFFu + ((u >> 16) & 1u)) >> 16);
}

// ---------------- CSR build ----------------

__global__ void count_kernel(const int* __restrict__ ei, int* __restrict__ deg) {
    int e = blockIdx.x * 256 + threadIdx.x;
    if (e < N_EDGES) atomicAdd(&deg[ei[N_EDGES + e]], 1);
}

__global__ __launch_bounds__(256)
void blocksum_kernel(const int* __restrict__ deg, int* __restrict__ bsum) {
    __shared__ int wsum[4];
    int t = threadIdx.x, lane = t & 63, w = t >> 6;
    int i = blockIdx.x * 256 + t;
    int v = (i < N_NODES) ? deg[i] : 0;
    #pragma unroll
    for (int d = 32; d >= 1; d >>= 1) v += __shfl_xor(v, d);
    if (lane == 0) wsum[w] = v;
    __syncthreads();
    if (t == 0) bsum[blockIdx.x] = wsum[0] + wsum[1] + wsum[2] + wsum[3];
}

__global__ __launch_bounds__(512)
void scanblk_kernel(const int* __restrict__ bsum, int* __restrict__ bbase,
                    int* __restrict__ off) {
    __shared__ int wsum[8];
    int t = threadIdx.x, lane = t & 63, w = t >> 6;
    int v = (t < NBLK) ? bsum[t] : 0;
    int incl = v;
    #pragma unroll
    for (int d = 1; d < 64; d <<= 1) {
        int u = __shfl_up(incl, d);
        if (lane >= d) incl += u;
    }
    if (lane == 63) wsum[w] = incl;
    __syncthreads();
    if (t < 8) {
        int s = wsum[t];
        int iv = s;
        #pragma unroll
        for (int d = 1; d < 8; d <<= 1) {
            int u = __shfl_up(iv, d, 8);
            if (t >= d) iv += u;
        }
        wsum[t] = iv - s;
    }
    __syncthreads();
    if (t < NBLK) bbase[t] = wsum[w] + (incl - v);
    if (t == 0) off[N_NODES] = N_EDGES;
}

__global__ __launch_bounds__(256)
void finalize_kernel(const int* __restrict__ deg, const int* __restrict__ bbase,
                     int* __restrict__ off, int* __restrict__ cursor,
                     float* __restrict__ dinv) {
    __shared__ int wsum[4];
    int t = threadIdx.x, lane = t & 63, w = t >> 6;
    int i = blockIdx.x * 256 + t;
    int v = (i < N_NODES) ? deg[i] : 0;
    int incl = v;
    #pragma unroll
    for (int d = 1; d < 64; d <<= 1) {
        int u = __shfl_up(incl, d);
        if (lane >= d) incl += u;
    }
    if (lane == 63) wsum[w] = incl;
    __syncthreads();
    if (t < 4) {
        int s = wsum[t];
        int iv = s;
        #pragma unroll
        for (int d = 1; d < 4; d <<= 1) {
            int u = __shfl_up(iv, d, 4);
            if (t >= d) iv += u;
        }
        wsum[t] = iv - s;
    }
    __syncthreads();
    if (i < N_NODES) {
        int excl = bbase[blockIdx.x] + wsum[w] + (incl - v);
        off[i] = excl;
        cursor[i] = excl;
        dinv[i] = 1.0f / (float)max(v, 1);
    }
}

__global__ void fill_kernel(const int* __restrict__ ei, int* __restrict__ cursor,
                            int* __restrict__ ssrc) {
    int e = blockIdx.x * 256 + threadIdx.x;
    if (e < N_EDGES) {
        int d = ei[N_EDGES + e];
        int p = atomicAdd(&cursor[d], 1);
        ssrc[p] = ei[e];
    }
}

// ---------------- W pre-split: concat [W1; W2] -> bf16 hi/lo ----------------

__global__ void wsplit_kernel(const float* __restrict__ W1, int n1,
                              const float* __restrict__ W2, int n2,
                              short* __restrict__ hi, short* __restrict__ lo) {
    int i = blockIdx.x * 256 + threadIdx.x;
    if (i >= n1 + n2) return;
    float a = (i < n1) ? W1[i] : W2[i - n1];
    short h, l;
    bsplit(a, h, l);
    hi[i] = h;
    lo[i] = l;
}

// ---------------- MFMA GEMM (split-bf16, 3-term) ----------------
// out1[N,C1](bf16) = H @ Wcat[0:C1]^T ; out2[N,C2](f32) = H @ Wcat[C1:]^T + bias2
// Block = 64 rows x (C1+C2) cols, 4 waves, wave w owns cols [w*(COUT/4), ...).
// No LDS; A loaded per-lane from global (block-local rows -> L1), W from pre-split bf16.
// In-place safe for out2 == H (block reads only its own rows; reads precede stores).

template<int C1, int C2>
__global__ __launch_bounds__(256)
void gemm_mfma(const float* __restrict__ H, const short* __restrict__ Whi,
               const short* __restrict__ Wlo, const float* __restrict__ bias2,
               ushort* __restrict__ out1, float* __restrict__ out2) {
    constexpr int COUT = C1 + C2;
    constexpr int CT = COUT / 64;        // col-tiles (of 16) per wave
    int t = threadIdx.x;
    int l = t & 63, w = t >> 6;
    int lr = l & 15;                     // row (A) / col (B,D) within tile
    int kg = l >> 4;                     // k-subgroup 0..3
    int r0 = blockIdx.x * 64;
    int c_base = w * (COUT / 4);
    const bool is1 = (c_base < C1);      // wave-uniform

    f32x4 acc[4][CT];
    #pragma unroll
    for (int m = 0; m < 4; ++m)
        #pragma unroll
        for (int c = 0; c < CT; ++c)
            acc[m][c] = (f32x4){0.f, 0.f, 0.f, 0.f};

    #pragma unroll
    for (int ks = 0; ks < 4; ++ks) {
        int k0 = ks * 32 + kg * 8;
        short8 ahi[4], alo[4];
        #pragma unroll
        for (int m = 0; m < 4; ++m) {
            int row = r0 + m * 16 + lr;
            float4 v0 = make_float4(0.f, 0.f, 0.f, 0.f), v1 = v0;
            if (row < N_NODES) {
                const float* p = &H[(size_t)row * 128 + k0];
                v0 = *reinterpret_cast<const float4*>(p);
                v1 = *reinterpret_cast<const float4*>(p + 4);
            }
            float av[8] = {v0.x, v0.y, v0.z, v0.w, v1.x, v1.y, v1.z, v1.w};
            #pragma unroll
            for (int j = 0; j < 8; ++j) {
                short h, lo2;
                bsplit(av[j], h, lo2);
                ahi[m][j] = h;
                alo[m][j] = lo2;
            }
        }
        short8 bhi[CT], blo[CT];
        #pragma unroll
        for (int c = 0; c < CT; ++c) {
            int col = c_base + c * 16 + lr;
            bhi[c] = *reinterpret_cast<const short8*>(&Whi[(size_t)col * 128 + k0]);
            blo[c] = *reinterpret_cast<const short8*>(&Wlo[(size_t)col * 128 + k0]);
        }
        #pragma unroll
        for (int m = 0; m < 4; ++m)
            #pragma unroll
            for (int c = 0; c < CT; ++c) {
                acc[m][c] = __builtin_amdgcn_mfma_f32_16x16x32_bf16(ahi[m], bhi[c], acc[m][c], 0, 0, 0);
                acc[m][c] = __builtin_amdgcn_mfma_f32_16x16x32_bf16(ahi[m], blo[c], acc[m][c], 0, 0, 0);
                acc[m][c] = __builtin_amdgcn_mfma_f32_16x16x32_bf16(alo[m], bhi[c], acc[m][c], 0, 0, 0);
            }
    }

    if (is1) {
        #pragma unroll
        for (int c = 0; c < CT; ++c) {
            int col = c_base + c * 16 + lr;
            #pragma unroll
            for (int m = 0; m < 4; ++m)
                #pragma unroll
                for (int r = 0; r < 4; ++r) {
                    int row = r0 + m * 16 + kg * 4 + r;
                    if (row < N_NODES)
                        out1[(size_t)row * C1 + col] = f2bf(acc[m][c][r]);
                }
        }
    } else {
        #pragma unroll
        for (int c = 0; c < CT; ++c) {
            int col = c_base - C1 + c * 16 + lr;
            float bb = bias2[col];
            #pragma unroll
            for (int m = 0; m < 4; ++m)
                #pragma unroll
                for (int r = 0; r < 4; ++r) {
                    int row = r0 + m * 16 + kg * 4 + r;
                    if (row < N_NODES)
                        out2[(size_t)row * C2 + col] = acc[m][c][r] + bb;
                }
        }
    }
}

// ---------------- Aggregate: out[i] = relu?(dinv[i]*sum_p Ybf[ssrc[p]] + out[i]) ----------------

template<int C, bool RELU>
__global__ __launch_bounds__(256)
void agg_kernel(const ushort* __restrict__ Y, const int* __restrict__ off,
                const int* __restrict__ ssrc, const float* __restrict__ dinv,
                float* out) {
    constexpr int CQ = C / 8;
    int tid = blockIdx.x * 256 + threadIdx.x;
    int i = tid / CQ, cq = tid % CQ;
    if (i >= N_NODES) return;
    int p0 = off[i], p1 = off[i + 1];
    float acc[8] = {0.f, 0.f, 0.f, 0.f, 0.f, 0.f, 0.f, 0.f};
    for (int p = p0; p < p1; ++p) {
        int s = ssrc[p];
        uint4 v = *reinterpret_cast<const uint4*>(&Y[(size_t)s * C + cq * 8]);
        uint32_t wd[4] = {v.x, v.y, v.z, v.w};
        #pragma unroll
        for (int j = 0; j < 4; ++j) {
            acc[2 * j]     += bfloat(wd[j] << 16);
            acc[2 * j + 1] += bfloat(wd[j] & 0xFFFF0000u);
        }
    }
    float di = dinv[i];
    float* op = &out[(size_t)i * C + cq * 8];
    float4 z0 = *reinterpret_cast<const float4*>(op);
    float4 z1 = *reinterpret_cast<const float4*>(op + 4);
    float zz[8] = {z0.x, z0.y, z0.z, z0.w, z1.x, z1.y, z1.z, z1.w};
    float r[8];
    #pragma unroll
    for (int j = 0; j < 8; ++j) {
        r[j] = acc[j] * di + zz[j];
        if (RELU) r[j] = fmaxf(r[j], 0.f);
    }
    float4 s0 = make_float4(r[0], r[1], r[2], r[3]);
    float4 s1 = make_float4(r[4], r[5], r[6], r[7]);
    *reinterpret_cast<float4*>(op) = s0;
    *reinterpret_cast<float4*>(op + 4) = s1;
}

// ---------------- launch ----------------

extern "C" void kernel_launch(void* const* d_in, const int* in_sizes, int n_in,
                              void* d_out, int out_size, void* d_ws, size_t ws_size,
                              hipStream_t stream) {
    const float* x   = (const float*)d_in[0];
    const int*   ei  = (const int*)d_in[2];
    const float* Wl0 = (const float*)d_in[3];
    const float* bl0 = (const float*)d_in[4];
    const float* Wr0 = (const float*)d_in[5];
    const float* Wl1 = (const float*)d_in[6];
    const float* bl1 = (const float*)d_in[7];
    const float* Wr1 = (const float*)d_in[8];
    const float* Wl2 = (const float*)d_in[9];
    const float* bl2 = (const float*)d_in[10];
    const float* Wr2 = (const float*)d_in[11];
    float* out = (float*)d_out;

    char* ws = (char*)d_ws;
    int*   deg    = (int*)(ws + 0);
    int*   off    = (int*)(ws + (size_t)(1 << 20));
    int*   cursor = (int*)(ws + (size_t)(2 << 20));
    float* dinv   = (float*)(ws + (size_t)(3 << 20));
    int*   bsum   = (int*)(ws + (size_t)(7 << 20) / 2);     // 3.5 MB
    int*   bbase  = (int*)(ws + (size_t)(15 << 20) / 4);    // 3.75 MB
    int*   ssrc   = (int*)(ws + (size_t)(4 << 20));         // 6.4 MB -> ends 10.4 MB
    short* w0hi   = (short*)(ws + (size_t)(11 << 20));
    short* w0lo   = w0hi + 32768;
    short* w1hi   = w0lo + 32768;
    short* w1lo   = w1hi + 32768;
    short* w2hi   = w1lo + 32768;
    short* w2lo   = w2hi + 16384;                            // ends < 11.4 MB
    ushort* Ybf   = (ushort*)(ws + (size_t)(12 << 20));      // 25.6 MB -> ends 37.6 MB
    float* bufB   = (float*)(ws + (size_t)(40 << 20));       // 51.2 MB -> ends 91.2 MB

    hipMemsetAsync(deg, 0, sizeof(int) * N_NODES, stream);

    int egrid = (N_EDGES + 255) / 256;
    count_kernel<<<egrid, 256, 0, stream>>>(ei, deg);
    blocksum_kernel<<<NBLK, 256, 0, stream>>>(deg, bsum);
    scanblk_kernel<<<1, 512, 0, stream>>>(bsum, bbase, off);
    finalize_kernel<<<NBLK, 256, 0, stream>>>(deg, bbase, off, cursor, dinv);
    fill_kernel<<<egrid, 256, 0, stream>>>(ei, cursor, ssrc);

    wsplit_kernel<<<128, 256, 0, stream>>>(Wl0, 16384, Wr0, 16384, w0hi, w0lo);
    wsplit_kernel<<<128, 256, 0, stream>>>(Wl1, 16384, Wr1, 16384, w1hi, w1lo);
    wsplit_kernel<<<64, 256, 0, stream>>>(Wl2, 8192, Wr2, 8192, w2hi, w2lo);

    int ggrid = (N_NODES + 63) / 64;                 // 1563
    int agrid128 = (N_NODES * 16 + 255) / 256;       // 6250
    int agrid64  = (N_NODES * 8 + 255) / 256;        // 3125

    // layer 0
    gemm_mfma<128, 128><<<ggrid, 256, 0, stream>>>(x, w0hi, w0lo, bl0, Ybf, bufB);
    agg_kernel<128, true><<<agrid128, 256, 0, stream>>>(Ybf, off, ssrc, dinv, bufB);

    // layer 1 (Z in-place on bufB)
    gemm_mfma<128, 128><<<ggrid, 256, 0, stream>>>(bufB, w1hi, w1lo, bl1, Ybf, bufB);
    agg_kernel<128, true><<<agrid128, 256, 0, stream>>>(Ybf, off, ssrc, dinv, bufB);

    // layer 2
    gemm_mfma<64, 64><<<ggrid, 256, 0, stream>>>(bufB, w2hi, w2lo, bl2, Ybf, out);
    agg_kernel<64, false><<<agrid64, 256, 0, stream>>>(Ybf, off, ssrc, dinv, out);
}